// Round 10
// baseline (434.844 us; speedup 1.0000x reference)
//
#include <hip/hip_runtime.h>

#define D_DIM 128
#define EDGE_DIM 32
#define BN_EPS 1e-5f

typedef __attribute__((ext_vector_type(8))) _Float16 f16x8;
typedef __attribute__((ext_vector_type(2))) _Float16 half2v;
typedef __attribute__((ext_vector_type(4))) float f32x4;
typedef unsigned short ushort_t;

__device__ __forceinline__ unsigned short f2h(float f) {
    union { _Float16 h; unsigned short u; } c;
    c.h = (_Float16)f;
    return c.u;
}
__device__ __forceinline__ unsigned pk2h(float lo, float hi) {
    return (unsigned)f2h(lo) | ((unsigned)f2h(hi) << 16);
}
__device__ __forceinline__ half2v asH2(unsigned u) {
    union { unsigned u; half2v h; } c;
    c.u = u;
    return c.h;
}
__device__ __forceinline__ float fdot2f(half2v a, half2v b, float c) {
#if __has_builtin(__builtin_amdgcn_fdot2)
    return __builtin_amdgcn_fdot2(a, b, c, false);
#else
    return c + (float)a.x * (float)b.x + (float)a.y * (float)b.y;
#endif
}

// ---------------------------------------------------------------------------
// CSR build: histogram -> multi-block scan -> scatter(+fp16 convert)
// ---------------------------------------------------------------------------
__global__ __launch_bounds__(256) void hist_kernel(
    const int* __restrict__ dst, int* __restrict__ cnt, int E)
{
    for (int e = blockIdx.x * 256 + threadIdx.x; e < E; e += gridDim.x * 256)
        atomicAdd(&cnt[dst[e]], 1);
}

__global__ __launch_bounds__(256) void scan_local_kernel(
    const int* __restrict__ cnt, int* __restrict__ off,
    int* __restrict__ blksum, int n)
{
    __shared__ int part[256];
    const int t = threadIdx.x;
    const int base = blockIdx.x * 2048 + t * 8;
    int v[8];
    int s = 0;
#pragma unroll
    for (int j = 0; j < 8; ++j) {
        const int idx = base + j;
        const int c = (idx < n) ? cnt[idx] : 0;
        v[j] = s;
        s += c;
    }
    part[t] = s;
    __syncthreads();
    for (int d = 1; d < 256; d <<= 1) {
        const int val = (t >= d) ? part[t - d] : 0;
        __syncthreads();
        part[t] += val;
        __syncthreads();
    }
    const int texcl = (t > 0) ? part[t - 1] : 0;
#pragma unroll
    for (int j = 0; j < 8; ++j) {
        const int idx = base + j;
        if (idx < n) off[idx] = texcl + v[j];
    }
    if (t == 255) blksum[blockIdx.x] = part[255];
}

__global__ __launch_bounds__(64) void scan_tops_kernel(
    int* __restrict__ blksum, int* __restrict__ off, int n, int B)
{
    if (threadIdx.x == 0) {
        int run = 0;
        for (int b = 0; b < B; ++b) {
            const int v = blksum[b];
            blksum[b] = run;
            run += v;
        }
        off[n] = run;
    }
}

__global__ __launch_bounds__(256) void scan_add_kernel(
    int* __restrict__ off, int* __restrict__ cur,
    const int* __restrict__ blksum, int n)
{
    const int base = blockIdx.x * 2048;
    const int add = blksum[blockIdx.x];
    for (int j = threadIdx.x; j < 2048; j += 256) {
        const int i = base + j;
        if (i < n) {
            const int v = off[i] + add;
            off[i] = v;
            cur[i] = v;
        }
    }
}

// scatter + inline edge_attr fp16 conversion into CSR order
__global__ __launch_bounds__(256) void scatter_conv_kernel(
    const int* __restrict__ src, const int* __restrict__ dst,
    const float* __restrict__ ea,
    int* __restrict__ cur, int* __restrict__ srcs,
    uint4* __restrict__ ea16q, int E)
{
    for (int e = blockIdx.x * 256 + threadIdx.x; e < E; e += gridDim.x * 256) {
        const int p = atomicAdd(&cur[dst[e]], 1);
        srcs[p] = src[e];
        const float* __restrict__ er = ea + (size_t)e * EDGE_DIM;
#pragma unroll
        for (int q = 0; q < 4; ++q) {
            const float4 a = *(const float4*)(er + q * 8);
            const float4 b = *(const float4*)(er + q * 8 + 4);
            uint4 o;
            o.x = pk2h(a.x, a.y); o.y = pk2h(a.z, a.w);
            o.z = pk2h(b.x, b.y); o.w = pk2h(b.z, b.w);
            ea16q[(size_t)p * 4 + q] = o;
        }
    }
}

// ---------------------------------------------------------------------------
// W_lin (32x128 fp32) -> k-pair-packed fp16
// ---------------------------------------------------------------------------
__global__ __launch_bounds__(256) void wl_build_kernel(
    const float* __restrict__ Wl, unsigned* __restrict__ wl16d)
{
#pragma unroll
    for (int r = 0; r < 8; ++r) {
        const int idx = r * 256 + threadIdx.x;
        const int kp = idx >> 7, c = idx & 127;
        wl16d[idx] = pk2h(Wl[(2 * kp) * D_DIM + c], Wl[(2 * kp + 1) * D_DIM + c]);
    }
}

// ---------------------------------------------------------------------------
// xprep0: fp32 x -> fp16 x16 (layer 0 only)
// ---------------------------------------------------------------------------
__global__ __launch_bounds__(256) void xprep0_kernel(
    const float* __restrict__ h, uint2* __restrict__ x16q, int M)
{
    const int total = M * 32;
    for (int i = blockIdx.x * 256 + threadIdx.x; i < total; i += gridDim.x * 256) {
        const float4 v = ((const float4*)h)[i];
        uint2 o; o.x = pk2h(v.x, v.y); o.y = pk2h(v.z, v.w);
        x16q[i] = o;
    }
}

// ---------------------------------------------------------------------------
// apply: x = relu(h16*sc + sh); emit fp16 x16 (OUTF32=0) or fp32 out (=1)
// ---------------------------------------------------------------------------
template<int OUTF32>
__global__ __launch_bounds__(256) void apply_kernel(
    const ushort_t* __restrict__ h16, const float* __restrict__ scsh,
    uint2* __restrict__ x16q, float* __restrict__ outp, int M)
{
    __shared__ float sc[128], sh[128];
    if (threadIdx.x < 128) {
        sc[threadIdx.x] = scsh[threadIdx.x];
        sh[threadIdx.x] = scsh[128 + threadIdx.x];
    }
    __syncthreads();
    const int total = M * 32;
    for (int i = blockIdx.x * 256 + threadIdx.x; i < total; i += gridDim.x * 256) {
        const uint2 hv = *(const uint2*)(h16 + (size_t)i * 4);
        const half2v a = asH2(hv.x), b = asH2(hv.y);
        const int c = (i & 31) * 4;
        const float v0 = fmaxf(fmaf((float)a.x, sc[c + 0], sh[c + 0]), 0.f);
        const float v1 = fmaxf(fmaf((float)a.y, sc[c + 1], sh[c + 1]), 0.f);
        const float v2 = fmaxf(fmaf((float)b.x, sc[c + 2], sh[c + 2]), 0.f);
        const float v3 = fmaxf(fmaf((float)b.y, sc[c + 3], sh[c + 3]), 0.f);
        if (OUTF32) {
            f32x4 o = {v0, v1, v2, v3};
            *(f32x4*)(outp + (size_t)i * 4) = o;
        } else {
            uint2 o; o.x = pk2h(v0, v1); o.y = pk2h(v2, v3);
            x16q[i] = o;
        }
    }
}

// ---------------------------------------------------------------------------
// Edge aggregation: one wave per node, fp16 gather + fdot2 matvec.
// __launch_bounds__(256,3): ~168 VGPR budget so W_lin columns (32 VGPRs)
// stay register-resident across the edge loop; manual 2-edge unroll with
// all loads hoisted ahead of the dot chains.
// ---------------------------------------------------------------------------
__global__ __launch_bounds__(256, 3) void edge_agg_kernel(
    const unsigned* __restrict__ x16d,
    const int*      __restrict__ srcs,
    const uint4*    __restrict__ ea16q,
    const int*      __restrict__ row_off,
    const unsigned* __restrict__ wl16d,
    const float*    __restrict__ bl,
    float*          __restrict__ agg,
    int nNodes)
{
    const int lane = threadIdx.x & 63;
    const int wid  = threadIdx.x >> 6;

    unsigned wA[16], wB[16];
#pragma unroll
    for (int kp = 0; kp < 16; ++kp) {
        const uint2 w2 = *(const uint2*)(wl16d + kp * 128 + 2 * lane);
        wA[kp] = w2.x; wB[kp] = w2.y;
    }
    const float b0 = bl[2 * lane];
    const float b1 = bl[2 * lane + 1];

    const int stride = gridDim.x * 4;
    for (int node = blockIdx.x * 4 + wid; node < nNodes; node += stride) {
        const int beg = __builtin_amdgcn_readfirstlane(row_off[node]);
        const int end = __builtin_amdgcn_readfirstlane(row_off[node + 1]);
        float acc0 = 0.f, acc1 = 0.f;

        int j = beg;
#pragma unroll 1
        for (; j + 1 < end; j += 2) {
            // ---- issue ALL loads for both edges first ----
            const int sA = srcs[j];
            const int sB = srcs[j + 1];
            const uint4 a0 = ea16q[(size_t)j * 4 + 0];
            const uint4 a1 = ea16q[(size_t)j * 4 + 1];
            const uint4 a2 = ea16q[(size_t)j * 4 + 2];
            const uint4 a3 = ea16q[(size_t)j * 4 + 3];
            const uint4 c0 = ea16q[(size_t)(j + 1) * 4 + 0];
            const uint4 c1 = ea16q[(size_t)(j + 1) * 4 + 1];
            const uint4 c2 = ea16q[(size_t)(j + 1) * 4 + 2];
            const uint4 c3 = ea16q[(size_t)(j + 1) * 4 + 3];
            const unsigned xdA = x16d[(size_t)sA * 64 + lane];
            const unsigned xdB = x16d[(size_t)sB * 64 + lane];

            const unsigned awA[16] = {a0.x, a0.y, a0.z, a0.w,
                                      a1.x, a1.y, a1.z, a1.w,
                                      a2.x, a2.y, a2.z, a2.w,
                                      a3.x, a3.y, a3.z, a3.w};
            const unsigned awB[16] = {c0.x, c0.y, c0.z, c0.w,
                                      c1.x, c1.y, c1.z, c1.w,
                                      c2.x, c2.y, c2.z, c2.w,
                                      c3.x, c3.y, c3.z, c3.w};
            float eA0 = b0, eA1 = b1, eB0 = b0, eB1 = b1;
#pragma unroll
            for (int kp = 0; kp < 16; ++kp) {
                eA0 = fdot2f(asH2(awA[kp]), asH2(wA[kp]), eA0);
                eA1 = fdot2f(asH2(awA[kp]), asH2(wB[kp]), eA1);
                eB0 = fdot2f(asH2(awB[kp]), asH2(wA[kp]), eB0);
                eB1 = fdot2f(asH2(awB[kp]), asH2(wB[kp]), eB1);
            }
            const half2v xhA = asH2(xdA);
            const half2v xhB = asH2(xdB);
            acc0 += fmaxf((float)xhA.x + eA0, 0.f) + fmaxf((float)xhB.x + eB0, 0.f);
            acc1 += fmaxf((float)xhA.y + eA1, 0.f) + fmaxf((float)xhB.y + eB1, 0.f);
        }
        if (j < end) {
            const int s = srcs[j];
            const uint4 a0 = ea16q[(size_t)j * 4 + 0];
            const uint4 a1 = ea16q[(size_t)j * 4 + 1];
            const uint4 a2 = ea16q[(size_t)j * 4 + 2];
            const uint4 a3 = ea16q[(size_t)j * 4 + 3];
            const unsigned xd = x16d[(size_t)s * 64 + lane];
            const unsigned aw[16] = {a0.x, a0.y, a0.z, a0.w,
                                     a1.x, a1.y, a1.z, a1.w,
                                     a2.x, a2.y, a2.z, a2.w,
                                     a3.x, a3.y, a3.z, a3.w};
            float e0 = b0, e1 = b1;
#pragma unroll
            for (int kp = 0; kp < 16; ++kp) {
                e0 = fdot2f(asH2(aw[kp]), asH2(wA[kp]), e0);
                e1 = fdot2f(asH2(aw[kp]), asH2(wB[kp]), e1);
            }
            const half2v xh = asH2(xd);
            acc0 += fmaxf((float)xh.x + e0, 0.f);
            acc1 += fmaxf((float)xh.y + e1, 0.f);
        }
        *(float2*)(agg + (size_t)node * D_DIM + 2 * lane) = make_float2(acc0, acc1);
    }
}

// ---------------------------------------------------------------------------
// Fused MLP: h16 = (relu((x16+agg)@W1+b1)) @ W2 + b2, fp16 out (pre-BN),
// + fused BN column sums/sumsq. h1 tile never leaves LDS.
// ---------------------------------------------------------------------------
__global__ __launch_bounds__(256) void fused_mlp_kernel(
    const unsigned* __restrict__ x16d,
    const float* __restrict__ agg,
    const float* __restrict__ W1,
    const float* __restrict__ b1,
    const float* __restrict__ W2,
    const float* __restrict__ b2,
    ushort_t* __restrict__ h16,
    float* __restrict__ sums,
    int M)
{
    __shared__ char ATb[128 * 256];
    __shared__ char WTb[128 * 256];
    __shared__ float bsum[256];
    const int tid = threadIdx.x;
    const int m0  = blockIdx.x * 128;

    bsum[tid] = 0.f;

#pragma unroll
    for (int i = 0; i < 16; ++i) {
        const int idx = i * 256 + tid;
        const int r = idx >> 5, c4 = idx & 31;
        const int row = m0 + r;
        f32x4 v = {0.f, 0.f, 0.f, 0.f};
        if (row < M) {
            const uint2 xv = *(const uint2*)(x16d + (size_t)row * 64 + c4 * 2);
            const f32x4 g  = *(const f32x4*)(agg + (size_t)row * 128 + c4 * 4);
            const half2v xa = asH2(xv.x), xb = asH2(xv.y);
            v[0] = (float)xa.x + g[0];
            v[1] = (float)xa.y + g[1];
            v[2] = (float)xb.x + g[2];
            v[3] = (float)xb.y + g[3];
        }
        uint2 p; p.x = pk2h(v[0], v[1]); p.y = pk2h(v[2], v[3]);
        *(uint2*)(ATb + r * 256 + ((c4 * 8) ^ ((r & 7) << 4))) = p;
    }
#pragma unroll
    for (int i = 0; i < 8; ++i) {
        const int c4 = (tid >> 6) + 4 * i;
        const int kp = tid & 63;
        const f32x4 wa = *(const f32x4*)(W1 + (size_t)(2 * kp) * 128 + c4 * 4);
        const f32x4 wb = *(const f32x4*)(W1 + (size_t)(2 * kp + 1) * 128 + c4 * 4);
#pragma unroll
        for (int j = 0; j < 4; ++j) {
            const int col = c4 * 4 + j;
            *(unsigned*)(WTb + col * 256 + ((kp * 4) ^ ((col & 7) << 4))) = pk2h(wa[j], wb[j]);
        }
    }
    __syncthreads();

    const int lane = tid & 63;
    const int w    = tid >> 6;
    const int fr   = lane & 15;
    const int fg   = lane >> 4;
    const int ar0  = w * 32 + fr;
    const int asz  = (ar0 & 7) << 4;

    f32x4 acc[2][8];
#pragma unroll
    for (int a = 0; a < 2; ++a)
#pragma unroll
        for (int b = 0; b < 8; ++b) acc[a][b] = (f32x4){0.f, 0.f, 0.f, 0.f};

#pragma unroll
    for (int ks = 0; ks < 4; ++ks) {
        const int kb = ks * 64 + fg * 16;
        const f16x8 a0 = *(const f16x8*)(ATb + ar0 * 256 + (kb ^ asz));
        const f16x8 a1 = *(const f16x8*)(ATb + (ar0 + 16) * 256 + (kb ^ asz));
#pragma unroll
        for (int cb = 0; cb < 8; ++cb) {
            const int col = cb * 16 + fr;
            const f16x8 b = *(const f16x8*)(WTb + col * 256 + (kb ^ ((col & 7) << 4)));
            acc[0][cb] = __builtin_amdgcn_mfma_f32_16x16x32_f16(a0, b, acc[0][cb], 0, 0, 0);
            acc[1][cb] = __builtin_amdgcn_mfma_f32_16x16x32_f16(a1, b, acc[1][cb], 0, 0, 0);
        }
    }
    __syncthreads();

    {
        float b1v[8];
#pragma unroll
        for (int cb = 0; cb < 8; ++cb) b1v[cb] = b1[cb * 16 + fr];
#pragma unroll
        for (int rf = 0; rf < 2; ++rf) {
            const int rb = w * 32 + rf * 16 + fg * 4;
#pragma unroll
            for (int cb = 0; cb < 8; ++cb) {
                const int c = cb * 16 + fr;
#pragma unroll
                for (int j = 0; j < 4; ++j) {
                    const int r = rb + j;
                    const float v = fmaxf(acc[rf][cb][j] + b1v[cb], 0.f);
                    *(ushort_t*)(ATb + r * 256 + ((c * 2) ^ ((r & 7) << 4))) = f2h(v);
                }
            }
        }
    }
#pragma unroll
    for (int i = 0; i < 8; ++i) {
        const int c4 = (tid >> 6) + 4 * i;
        const int kp = tid & 63;
        const f32x4 wa = *(const f32x4*)(W2 + (size_t)(2 * kp) * 128 + c4 * 4);
        const f32x4 wb = *(const f32x4*)(W2 + (size_t)(2 * kp + 1) * 128 + c4 * 4);
#pragma unroll
        for (int j = 0; j < 4; ++j) {
            const int col = c4 * 4 + j;
            *(unsigned*)(WTb + col * 256 + ((kp * 4) ^ ((col & 7) << 4))) = pk2h(wa[j], wb[j]);
        }
    }
#pragma unroll
    for (int a = 0; a < 2; ++a)
#pragma unroll
        for (int b = 0; b < 8; ++b) acc[a][b] = (f32x4){0.f, 0.f, 0.f, 0.f};
    __syncthreads();

#pragma unroll
    for (int ks = 0; ks < 4; ++ks) {
        const int kb = ks * 64 + fg * 16;
        const f16x8 a0 = *(const f16x8*)(ATb + ar0 * 256 + (kb ^ asz));
        const f16x8 a1 = *(const f16x8*)(ATb + (ar0 + 16) * 256 + (kb ^ asz));
#pragma unroll
        for (int cb = 0; cb < 8; ++cb) {
            const int col = cb * 16 + fr;
            const f16x8 b = *(const f16x8*)(WTb + col * 256 + (kb ^ ((col & 7) << 4)));
            acc[0][cb] = __builtin_amdgcn_mfma_f32_16x16x32_f16(a0, b, acc[0][cb], 0, 0, 0);
            acc[1][cb] = __builtin_amdgcn_mfma_f32_16x16x32_f16(a1, b, acc[1][cb], 0, 0, 0);
        }
    }

    float b2v[8];
#pragma unroll
    for (int cb = 0; cb < 8; ++cb) b2v[cb] = b2[cb * 16 + fr];
    float s[8], q[8];
#pragma unroll
    for (int cb = 0; cb < 8; ++cb) { s[cb] = 0.f; q[cb] = 0.f; }

#pragma unroll
    for (int rf = 0; rf < 2; ++rf) {
        const int r0 = m0 + w * 32 + rf * 16 + fg * 4;
#pragma unroll
        for (int cb = 0; cb < 8; ++cb) {
            const int col = cb * 16 + fr;
#pragma unroll
            for (int j = 0; j < 4; ++j) {
                const int row = r0 + j;
                if (row < M) {
                    const float v = acc[rf][cb][j] + b2v[cb];
                    h16[(size_t)row * 128 + col] = f2h(v);
                    s[cb] += v;
                    q[cb] += v * v;
                }
            }
        }
    }
#pragma unroll
    for (int cb = 0; cb < 8; ++cb) {
        float ss = s[cb]; ss += __shfl_down(ss, 32); ss += __shfl_down(ss, 16);
        float qq = q[cb]; qq += __shfl_down(qq, 32); qq += __shfl_down(qq, 16);
        if (lane < 16) {
            atomicAdd(&bsum[cb * 16 + lane], ss);
            atomicAdd(&bsum[128 + cb * 16 + lane], qq);
        }
    }
    __syncthreads();
    unsafeAtomicAdd(&sums[tid], bsum[tid]);
}

// ---------------------------------------------------------------------------
__global__ __launch_bounds__(128) void bn_finalize_kernel(
    const float* __restrict__ sums,
    const float* __restrict__ gamma, const float* __restrict__ beta,
    float* __restrict__ scsh, float invM)
{
    const int c = threadIdx.x;
    const float mu  = sums[c] * invM;
    const float var = sums[128 + c] * invM - mu * mu;
    const float sc  = gamma[c] * rsqrtf(var + BN_EPS);
    scsh[c]       = sc;
    scsh[128 + c] = beta[c] - mu * sc;
}

// ---------------------------------------------------------------------------
extern "C" void kernel_launch(void* const* d_in, const int* in_sizes, int n_in,
                              void* d_out, int out_size, void* d_ws, size_t ws_size,
                              hipStream_t stream)
{
    const float* x_in  = (const float*)d_in[0];
    const int*   ei    = (const int*)  d_in[1];
    const float* ea    = (const float*)d_in[2];
    const float* W_lin = (const float*)d_in[3];
    const float* b_lin = (const float*)d_in[4];
    const float* W1    = (const float*)d_in[5];
    const float* b1    = (const float*)d_in[6];
    const float* W2    = (const float*)d_in[7];
    const float* b2    = (const float*)d_in[8];
    const float* gamma = (const float*)d_in[9];
    const float* beta  = (const float*)d_in[10];

    const int N = in_sizes[0] / D_DIM;              // 50000
    const int E = in_sizes[2] / EDGE_DIM;           // 600000
    const int L = in_sizes[3] / (EDGE_DIM * D_DIM); // 3

    const int* src = ei;
    const int* dst = ei + E;

    float* out = (float*)d_out;

    char* wp = (char*)d_ws;
    auto take = [&wp](size_t bytes) {
        char* r = wp;
        wp += (bytes + 15) & ~(size_t)15;
        return r;
    };
    float*     agg     = (float*)    take((size_t)N * D_DIM * 4);
    ushort_t*  h16     = (ushort_t*) take((size_t)N * D_DIM * 2);
    unsigned*  x16d    = (unsigned*) take((size_t)N * D_DIM * 2);
    float*     sums    = (float*)    take(256 * 4);
    float*     scsh    = (float*)    take(256 * 4);
    unsigned*  wl16d   = (unsigned*) take(16 * 128 * 4);
    int*       cnt     = (int*)      take((size_t)N * 4);
    int*       row_off = (int*)      take((size_t)(N + 1) * 4);
    int*       cur     = (int*)      take((size_t)N * 4);
    int*       blksum  = (int*)      take(256 * 4);
    int*       srcs    = (int*)      take((size_t)E * 4);
    uint4*     ea16q   = (uint4*)    take((size_t)E * 64);

    const int gemmBlocks = (N + 127) / 128;
    const int scanBlocks = (N + 2047) / 2048;

    hipMemsetAsync(cnt, 0, (size_t)N * sizeof(int), stream);
    hist_kernel<<<1024, 256, 0, stream>>>(dst, cnt, E);
    scan_local_kernel<<<scanBlocks, 256, 0, stream>>>(cnt, row_off, blksum, N);
    scan_tops_kernel<<<1, 64, 0, stream>>>(blksum, row_off, N, scanBlocks);
    scan_add_kernel<<<scanBlocks, 256, 0, stream>>>(row_off, cur, blksum, N);
    scatter_conv_kernel<<<1024, 256, 0, stream>>>(src, dst, ea, cur, srcs, ea16q, E);

    for (int l = 0; l < L; ++l) {
        hipMemsetAsync(sums, 0, 256 * sizeof(float), stream);

        const float* Wl_l = W_lin + (size_t)l * EDGE_DIM * D_DIM;
        const float* bl_l = b_lin + (size_t)l * D_DIM;
        const float* W1_l = W1 + (size_t)l * D_DIM * D_DIM;
        const float* b1_l = b1 + (size_t)l * D_DIM;
        const float* W2_l = W2 + (size_t)l * D_DIM * D_DIM;
        const float* b2_l = b2 + (size_t)l * D_DIM;

        if (l == 0)
            xprep0_kernel<<<1024, 256, 0, stream>>>(x_in, (uint2*)x16d, N);
        else
            apply_kernel<0><<<1024, 256, 0, stream>>>(h16, scsh, (uint2*)x16d, nullptr, N);

        wl_build_kernel<<<1, 256, 0, stream>>>(Wl_l, wl16d);

        edge_agg_kernel<<<2048, 256, 0, stream>>>(
            x16d, srcs, ea16q, row_off, wl16d, bl_l, agg, N);

        fused_mlp_kernel<<<gemmBlocks, 256, 0, stream>>>(
            x16d, agg, W1_l, b1_l, W2_l, b2_l, h16, sums, N);

        bn_finalize_kernel<<<1, 128, 0, stream>>>(
            sums, gamma + (size_t)l * D_DIM, beta + (size_t)l * D_DIM,
            scsh, 1.f / (float)N);
    }

    apply_kernel<1><<<1024, 256, 0, stream>>>(h16, scsh, nullptr, out, N);
}

// Round 11
// 428.322 us; speedup vs baseline: 1.0152x; 1.0152x over previous
//
#include <hip/hip_runtime.h>

#define D_DIM 128
#define EDGE_DIM 32
#define BN_EPS 1e-5f

typedef __attribute__((ext_vector_type(8))) _Float16 f16x8;
typedef __attribute__((ext_vector_type(2))) _Float16 half2v;
typedef __attribute__((ext_vector_type(4))) float f32x4;
typedef unsigned short ushort_t;

__device__ __forceinline__ unsigned short f2h(float f) {
    union { _Float16 h; unsigned short u; } c;
    c.h = (_Float16)f;
    return c.u;
}
__device__ __forceinline__ unsigned pk2h(float lo, float hi) {
    return (unsigned)f2h(lo) | ((unsigned)f2h(hi) << 16);
}
__device__ __forceinline__ half2v asH2(unsigned u) {
    union { unsigned u; half2v h; } c;
    c.u = u;
    return c.h;
}
__device__ __forceinline__ float fdot2f(half2v a, half2v b, float c) {
#if __has_builtin(__builtin_amdgcn_fdot2)
    return __builtin_amdgcn_fdot2(a, b, c, false);
#else
    return c + (float)a.x * (float)b.x + (float)a.y * (float)b.y;
#endif
}

// ---------------------------------------------------------------------------
// CSR build: histogram -> multi-block scan -> scatter(+fp16 convert)
// ---------------------------------------------------------------------------
__global__ __launch_bounds__(256) void hist_kernel(
    const int* __restrict__ dst, int* __restrict__ cnt, int E)
{
    for (int e = blockIdx.x * 256 + threadIdx.x; e < E; e += gridDim.x * 256)
        atomicAdd(&cnt[dst[e]], 1);
}

__global__ __launch_bounds__(256) void scan_local_kernel(
    const int* __restrict__ cnt, int* __restrict__ off,
    int* __restrict__ blksum, int n)
{
    __shared__ int part[256];
    const int t = threadIdx.x;
    const int base = blockIdx.x * 2048 + t * 8;
    int v[8];
    int s = 0;
#pragma unroll
    for (int j = 0; j < 8; ++j) {
        const int idx = base + j;
        const int c = (idx < n) ? cnt[idx] : 0;
        v[j] = s;
        s += c;
    }
    part[t] = s;
    __syncthreads();
    for (int d = 1; d < 256; d <<= 1) {
        const int val = (t >= d) ? part[t - d] : 0;
        __syncthreads();
        part[t] += val;
        __syncthreads();
    }
    const int texcl = (t > 0) ? part[t - 1] : 0;
#pragma unroll
    for (int j = 0; j < 8; ++j) {
        const int idx = base + j;
        if (idx < n) off[idx] = texcl + v[j];
    }
    if (t == 255) blksum[blockIdx.x] = part[255];
}

__global__ __launch_bounds__(64) void scan_tops_kernel(
    int* __restrict__ blksum, int* __restrict__ off, int n, int B)
{
    if (threadIdx.x == 0) {
        int run = 0;
        for (int b = 0; b < B; ++b) {
            const int v = blksum[b];
            blksum[b] = run;
            run += v;
        }
        off[n] = run;
    }
}

__global__ __launch_bounds__(256) void scan_add_kernel(
    int* __restrict__ off, int* __restrict__ cur,
    const int* __restrict__ blksum, int n)
{
    const int base = blockIdx.x * 2048;
    const int add = blksum[blockIdx.x];
    for (int j = threadIdx.x; j < 2048; j += 256) {
        const int i = base + j;
        if (i < n) {
            const int v = off[i] + add;
            off[i] = v;
            cur[i] = v;
        }
    }
}

// scatter + inline edge_attr fp16 conversion into CSR order
__global__ __launch_bounds__(256) void scatter_conv_kernel(
    const int* __restrict__ src, const int* __restrict__ dst,
    const float* __restrict__ ea,
    int* __restrict__ cur, int* __restrict__ srcs,
    uint4* __restrict__ ea16q, int E)
{
    for (int e = blockIdx.x * 256 + threadIdx.x; e < E; e += gridDim.x * 256) {
        const int p = atomicAdd(&cur[dst[e]], 1);
        srcs[p] = src[e];
        const float* __restrict__ er = ea + (size_t)e * EDGE_DIM;
#pragma unroll
        for (int q = 0; q < 4; ++q) {
            const float4 a = *(const float4*)(er + q * 8);
            const float4 b = *(const float4*)(er + q * 8 + 4);
            uint4 o;
            o.x = pk2h(a.x, a.y); o.y = pk2h(a.z, a.w);
            o.z = pk2h(b.x, b.y); o.w = pk2h(b.z, b.w);
            ea16q[(size_t)p * 4 + q] = o;
        }
    }
}

// ---------------------------------------------------------------------------
// W_lin (32x128 fp32) -> k-pair-packed fp16
// ---------------------------------------------------------------------------
__global__ __launch_bounds__(256) void wl_build_kernel(
    const float* __restrict__ Wl, unsigned* __restrict__ wl16d)
{
#pragma unroll
    for (int r = 0; r < 8; ++r) {
        const int idx = r * 256 + threadIdx.x;
        const int kp = idx >> 7, c = idx & 127;
        wl16d[idx] = pk2h(Wl[(2 * kp) * D_DIM + c], Wl[(2 * kp + 1) * D_DIM + c]);
    }
}

// ---------------------------------------------------------------------------
// xprep0: fp32 x -> fp16 x16 (layer 0 only)
// ---------------------------------------------------------------------------
__global__ __launch_bounds__(256) void xprep0_kernel(
    const float* __restrict__ h, uint2* __restrict__ x16q, int M)
{
    const int total = M * 32;
    for (int i = blockIdx.x * 256 + threadIdx.x; i < total; i += gridDim.x * 256) {
        const float4 v = ((const float4*)h)[i];
        uint2 o; o.x = pk2h(v.x, v.y); o.y = pk2h(v.z, v.w);
        x16q[i] = o;
    }
}

// ---------------------------------------------------------------------------
// apply: x = relu(h16*sc + sh); emit fp16 x16 (OUTF32=0) or fp32 out (=1)
// ---------------------------------------------------------------------------
template<int OUTF32>
__global__ __launch_bounds__(256) void apply_kernel(
    const ushort_t* __restrict__ h16, const float* __restrict__ scsh,
    uint2* __restrict__ x16q, float* __restrict__ outp, int M)
{
    __shared__ float sc[128], sh[128];
    if (threadIdx.x < 128) {
        sc[threadIdx.x] = scsh[threadIdx.x];
        sh[threadIdx.x] = scsh[128 + threadIdx.x];
    }
    __syncthreads();
    const int total = M * 32;
    for (int i = blockIdx.x * 256 + threadIdx.x; i < total; i += gridDim.x * 256) {
        const uint2 hv = *(const uint2*)(h16 + (size_t)i * 4);
        const half2v a = asH2(hv.x), b = asH2(hv.y);
        const int c = (i & 31) * 4;
        const float v0 = fmaxf(fmaf((float)a.x, sc[c + 0], sh[c + 0]), 0.f);
        const float v1 = fmaxf(fmaf((float)a.y, sc[c + 1], sh[c + 1]), 0.f);
        const float v2 = fmaxf(fmaf((float)b.x, sc[c + 2], sh[c + 2]), 0.f);
        const float v3 = fmaxf(fmaf((float)b.y, sc[c + 3], sh[c + 3]), 0.f);
        if (OUTF32) {
            f32x4 o = {v0, v1, v2, v3};
            *(f32x4*)(outp + (size_t)i * 4) = o;
        } else {
            uint2 o; o.x = pk2h(v0, v1); o.y = pk2h(v2, v3);
            x16q[i] = o;
        }
    }
}

// ---------------------------------------------------------------------------
// Edge aggregation: one wave per node, fp16 gather + fdot2 matvec.
// W_lin columns PINNED in VGPRs via asm keep-alive (compiler cannot
// rematerialize); srcs prefetched one pair ahead; x-gathers issued before
// ea loads; dot chains split (depth 8 x 8 chains) for dep-latency hiding.
// ---------------------------------------------------------------------------
__global__ __launch_bounds__(256, 2) void edge_agg_kernel(
    const unsigned* __restrict__ x16d,
    const int*      __restrict__ srcs,
    const uint4*    __restrict__ ea16q,
    const int*      __restrict__ row_off,
    const unsigned* __restrict__ wl16d,
    const float*    __restrict__ bl,
    float*          __restrict__ agg,
    int nNodes)
{
    const int lane = threadIdx.x & 63;
    const int wid  = threadIdx.x >> 6;

    unsigned wA[16], wB[16];
#pragma unroll
    for (int kp = 0; kp < 16; ++kp) {
        const uint2 w2 = *(const uint2*)(wl16d + kp * 128 + 2 * lane);
        wA[kp] = w2.x; wB[kp] = w2.y;
    }
    // Pin the 32 W registers: opaque asm producer defeats rematerialization.
#pragma unroll
    for (int kp = 0; kp < 16; ++kp) {
        asm volatile("" : "+v"(wA[kp]));
        asm volatile("" : "+v"(wB[kp]));
    }
    const float b0 = bl[2 * lane];
    const float b1 = bl[2 * lane + 1];

    const int stride = gridDim.x * 4;
    for (int node = blockIdx.x * 4 + wid; node < nNodes; node += stride) {
        const int beg = __builtin_amdgcn_readfirstlane(row_off[node]);
        const int end = __builtin_amdgcn_readfirstlane(row_off[node + 1]);
        float acc0 = 0.f, acc1 = 0.f;

        const int nPair = (end - beg) >> 1;
        int j = beg;
        int sA = 0, sB = 0;
        if (nPair > 0) { sA = srcs[j]; sB = srcs[j + 1]; }

#pragma unroll 1
        for (int it = 0; it < nPair; ++it) {
            // x-gathers for current pair first (longest latency)
            const unsigned xdA = x16d[(size_t)sA * 64 + lane];
            const unsigned xdB = x16d[(size_t)sB * 64 + lane];
            // prefetch next pair's src indices
            int sA2 = sA, sB2 = sB;
            if (it + 1 < nPair) {
                sA2 = srcs[j + 2];
                sB2 = srcs[j + 3];
            }
            // ea vectors for current pair
            const uint4 a0 = ea16q[(size_t)j * 4 + 0];
            const uint4 a1 = ea16q[(size_t)j * 4 + 1];
            const uint4 a2 = ea16q[(size_t)j * 4 + 2];
            const uint4 a3 = ea16q[(size_t)j * 4 + 3];
            const uint4 c0 = ea16q[(size_t)(j + 1) * 4 + 0];
            const uint4 c1 = ea16q[(size_t)(j + 1) * 4 + 1];
            const uint4 c2 = ea16q[(size_t)(j + 1) * 4 + 2];
            const uint4 c3 = ea16q[(size_t)(j + 1) * 4 + 3];

            const unsigned awA[16] = {a0.x, a0.y, a0.z, a0.w,
                                      a1.x, a1.y, a1.z, a1.w,
                                      a2.x, a2.y, a2.z, a2.w,
                                      a3.x, a3.y, a3.z, a3.w};
            const unsigned awB[16] = {c0.x, c0.y, c0.z, c0.w,
                                      c1.x, c1.y, c1.z, c1.w,
                                      c2.x, c2.y, c2.z, c2.w,
                                      c3.x, c3.y, c3.z, c3.w};
            // 8 independent chains of depth 8
            float pA0 = b0, pA1 = b1, pB0 = b0, pB1 = b1;
            float qA0 = 0.f, qA1 = 0.f, qB0 = 0.f, qB1 = 0.f;
#pragma unroll
            for (int kp = 0; kp < 8; ++kp) {
                pA0 = fdot2f(asH2(awA[kp]), asH2(wA[kp]), pA0);
                pA1 = fdot2f(asH2(awA[kp]), asH2(wB[kp]), pA1);
                pB0 = fdot2f(asH2(awB[kp]), asH2(wA[kp]), pB0);
                pB1 = fdot2f(asH2(awB[kp]), asH2(wB[kp]), pB1);
                qA0 = fdot2f(asH2(awA[kp + 8]), asH2(wA[kp + 8]), qA0);
                qA1 = fdot2f(asH2(awA[kp + 8]), asH2(wB[kp + 8]), qA1);
                qB0 = fdot2f(asH2(awB[kp + 8]), asH2(wA[kp + 8]), qB0);
                qB1 = fdot2f(asH2(awB[kp + 8]), asH2(wB[kp + 8]), qB1);
            }
            const half2v xhA = asH2(xdA);
            const half2v xhB = asH2(xdB);
            acc0 += fmaxf((float)xhA.x + pA0 + qA0, 0.f)
                  + fmaxf((float)xhB.x + pB0 + qB0, 0.f);
            acc1 += fmaxf((float)xhA.y + pA1 + qA1, 0.f)
                  + fmaxf((float)xhB.y + pB1 + qB1, 0.f);
            sA = sA2; sB = sB2;
            j += 2;
        }
        if (j < end) {   // odd leftover edge
            const int s = srcs[j];
            const unsigned xd = x16d[(size_t)s * 64 + lane];
            const uint4 a0 = ea16q[(size_t)j * 4 + 0];
            const uint4 a1 = ea16q[(size_t)j * 4 + 1];
            const uint4 a2 = ea16q[(size_t)j * 4 + 2];
            const uint4 a3 = ea16q[(size_t)j * 4 + 3];
            const unsigned aw[16] = {a0.x, a0.y, a0.z, a0.w,
                                     a1.x, a1.y, a1.z, a1.w,
                                     a2.x, a2.y, a2.z, a2.w,
                                     a3.x, a3.y, a3.z, a3.w};
            float p0 = b0, p1 = b1, q0 = 0.f, q1 = 0.f;
#pragma unroll
            for (int kp = 0; kp < 8; ++kp) {
                p0 = fdot2f(asH2(aw[kp]), asH2(wA[kp]), p0);
                p1 = fdot2f(asH2(aw[kp]), asH2(wB[kp]), p1);
                q0 = fdot2f(asH2(aw[kp + 8]), asH2(wA[kp + 8]), q0);
                q1 = fdot2f(asH2(aw[kp + 8]), asH2(wB[kp + 8]), q1);
            }
            const half2v xh = asH2(xd);
            acc0 += fmaxf((float)xh.x + p0 + q0, 0.f);
            acc1 += fmaxf((float)xh.y + p1 + q1, 0.f);
        }
        *(float2*)(agg + (size_t)node * D_DIM + 2 * lane) = make_float2(acc0, acc1);
    }
}

// ---------------------------------------------------------------------------
// Fused MLP: h16 = (relu((x16+agg)@W1+b1)) @ W2 + b2, fp16 out (pre-BN),
// + fused BN column sums/sumsq. h1 tile never leaves LDS.
// ---------------------------------------------------------------------------
__global__ __launch_bounds__(256) void fused_mlp_kernel(
    const unsigned* __restrict__ x16d,
    const float* __restrict__ agg,
    const float* __restrict__ W1,
    const float* __restrict__ b1,
    const float* __restrict__ W2,
    const float* __restrict__ b2,
    ushort_t* __restrict__ h16,
    float* __restrict__ sums,
    int M)
{
    __shared__ char ATb[128 * 256];
    __shared__ char WTb[128 * 256];
    __shared__ float bsum[256];
    const int tid = threadIdx.x;
    const int m0  = blockIdx.x * 128;

    bsum[tid] = 0.f;

#pragma unroll
    for (int i = 0; i < 16; ++i) {
        const int idx = i * 256 + tid;
        const int r = idx >> 5, c4 = idx & 31;
        const int row = m0 + r;
        f32x4 v = {0.f, 0.f, 0.f, 0.f};
        if (row < M) {
            const uint2 xv = *(const uint2*)(x16d + (size_t)row * 64 + c4 * 2);
            const f32x4 g  = *(const f32x4*)(agg + (size_t)row * 128 + c4 * 4);
            const half2v xa = asH2(xv.x), xb = asH2(xv.y);
            v[0] = (float)xa.x + g[0];
            v[1] = (float)xa.y + g[1];
            v[2] = (float)xb.x + g[2];
            v[3] = (float)xb.y + g[3];
        }
        uint2 p; p.x = pk2h(v[0], v[1]); p.y = pk2h(v[2], v[3]);
        *(uint2*)(ATb + r * 256 + ((c4 * 8) ^ ((r & 7) << 4))) = p;
    }
#pragma unroll
    for (int i = 0; i < 8; ++i) {
        const int c4 = (tid >> 6) + 4 * i;
        const int kp = tid & 63;
        const f32x4 wa = *(const f32x4*)(W1 + (size_t)(2 * kp) * 128 + c4 * 4);
        const f32x4 wb = *(const f32x4*)(W1 + (size_t)(2 * kp + 1) * 128 + c4 * 4);
#pragma unroll
        for (int j = 0; j < 4; ++j) {
            const int col = c4 * 4 + j;
            *(unsigned*)(WTb + col * 256 + ((kp * 4) ^ ((col & 7) << 4))) = pk2h(wa[j], wb[j]);
        }
    }
    __syncthreads();

    const int lane = tid & 63;
    const int w    = tid >> 6;
    const int fr   = lane & 15;
    const int fg   = lane >> 4;
    const int ar0  = w * 32 + fr;
    const int asz  = (ar0 & 7) << 4;

    f32x4 acc[2][8];
#pragma unroll
    for (int a = 0; a < 2; ++a)
#pragma unroll
        for (int b = 0; b < 8; ++b) acc[a][b] = (f32x4){0.f, 0.f, 0.f, 0.f};

#pragma unroll
    for (int ks = 0; ks < 4; ++ks) {
        const int kb = ks * 64 + fg * 16;
        const f16x8 a0 = *(const f16x8*)(ATb + ar0 * 256 + (kb ^ asz));
        const f16x8 a1 = *(const f16x8*)(ATb + (ar0 + 16) * 256 + (kb ^ asz));
#pragma unroll
        for (int cb = 0; cb < 8; ++cb) {
            const int col = cb * 16 + fr;
            const f16x8 b = *(const f16x8*)(WTb + col * 256 + (kb ^ ((col & 7) << 4)));
            acc[0][cb] = __builtin_amdgcn_mfma_f32_16x16x32_f16(a0, b, acc[0][cb], 0, 0, 0);
            acc[1][cb] = __builtin_amdgcn_mfma_f32_16x16x32_f16(a1, b, acc[1][cb], 0, 0, 0);
        }
    }
    __syncthreads();

    {
        float b1v[8];
#pragma unroll
        for (int cb = 0; cb < 8; ++cb) b1v[cb] = b1[cb * 16 + fr];
#pragma unroll
        for (int rf = 0; rf < 2; ++rf) {
            const int rb = w * 32 + rf * 16 + fg * 4;
#pragma unroll
            for (int cb = 0; cb < 8; ++cb) {
                const int c = cb * 16 + fr;
#pragma unroll
                for (int j = 0; j < 4; ++j) {
                    const int r = rb + j;
                    const float v = fmaxf(acc[rf][cb][j] + b1v[cb], 0.f);
                    *(ushort_t*)(ATb + r * 256 + ((c * 2) ^ ((r & 7) << 4))) = f2h(v);
                }
            }
        }
    }
#pragma unroll
    for (int i = 0; i < 8; ++i) {
        const int c4 = (tid >> 6) + 4 * i;
        const int kp = tid & 63;
        const f32x4 wa = *(const f32x4*)(W2 + (size_t)(2 * kp) * 128 + c4 * 4);
        const f32x4 wb = *(const f32x4*)(W2 + (size_t)(2 * kp + 1) * 128 + c4 * 4);
#pragma unroll
        for (int j = 0; j < 4; ++j) {
            const int col = c4 * 4 + j;
            *(unsigned*)(WTb + col * 256 + ((kp * 4) ^ ((col & 7) << 4))) = pk2h(wa[j], wb[j]);
        }
    }
#pragma unroll
    for (int a = 0; a < 2; ++a)
#pragma unroll
        for (int b = 0; b < 8; ++b) acc[a][b] = (f32x4){0.f, 0.f, 0.f, 0.f};
    __syncthreads();

#pragma unroll
    for (int ks = 0; ks < 4; ++ks) {
        const int kb = ks * 64 + fg * 16;
        const f16x8 a0 = *(const f16x8*)(ATb + ar0 * 256 + (kb ^ asz));
        const f16x8 a1 = *(const f16x8*)(ATb + (ar0 + 16) * 256 + (kb ^ asz));
#pragma unroll
        for (int cb = 0; cb < 8; ++cb) {
            const int col = cb * 16 + fr;
            const f16x8 b = *(const f16x8*)(WTb + col * 256 + (kb ^ ((col & 7) << 4)));
            acc[0][cb] = __builtin_amdgcn_mfma_f32_16x16x32_f16(a0, b, acc[0][cb], 0, 0, 0);
            acc[1][cb] = __builtin_amdgcn_mfma_f32_16x16x32_f16(a1, b, acc[1][cb], 0, 0, 0);
        }
    }

    float b2v[8];
#pragma unroll
    for (int cb = 0; cb < 8; ++cb) b2v[cb] = b2[cb * 16 + fr];
    float s[8], q[8];
#pragma unroll
    for (int cb = 0; cb < 8; ++cb) { s[cb] = 0.f; q[cb] = 0.f; }

#pragma unroll
    for (int rf = 0; rf < 2; ++rf) {
        const int r0 = m0 + w * 32 + rf * 16 + fg * 4;
#pragma unroll
        for (int cb = 0; cb < 8; ++cb) {
            const int col = cb * 16 + fr;
#pragma unroll
            for (int j = 0; j < 4; ++j) {
                const int row = r0 + j;
                if (row < M) {
                    const float v = acc[rf][cb][j] + b2v[cb];
                    h16[(size_t)row * 128 + col] = f2h(v);
                    s[cb] += v;
                    q[cb] += v * v;
                }
            }
        }
    }
#pragma unroll
    for (int cb = 0; cb < 8; ++cb) {
        float ss = s[cb]; ss += __shfl_down(ss, 32); ss += __shfl_down(ss, 16);
        float qq = q[cb]; qq += __shfl_down(qq, 32); qq += __shfl_down(qq, 16);
        if (lane < 16) {
            atomicAdd(&bsum[cb * 16 + lane], ss);
            atomicAdd(&bsum[128 + cb * 16 + lane], qq);
        }
    }
    __syncthreads();
    unsafeAtomicAdd(&sums[tid], bsum[tid]);
}

// ---------------------------------------------------------------------------
__global__ __launch_bounds__(128) void bn_finalize_kernel(
    const float* __restrict__ sums,
    const float* __restrict__ gamma, const float* __restrict__ beta,
    float* __restrict__ scsh, float invM)
{
    const int c = threadIdx.x;
    const float mu  = sums[c] * invM;
    const float var = sums[128 + c] * invM - mu * mu;
    const float sc  = gamma[c] * rsqrtf(var + BN_EPS);
    scsh[c]       = sc;
    scsh[128 + c] = beta[c] - mu * sc;
}

// ---------------------------------------------------------------------------
extern "C" void kernel_launch(void* const* d_in, const int* in_sizes, int n_in,
                              void* d_out, int out_size, void* d_ws, size_t ws_size,
                              hipStream_t stream)
{
    const float* x_in  = (const float*)d_in[0];
    const int*   ei    = (const int*)  d_in[1];
    const float* ea    = (const float*)d_in[2];
    const float* W_lin = (const float*)d_in[3];
    const float* b_lin = (const float*)d_in[4];
    const float* W1    = (const float*)d_in[5];
    const float* b1    = (const float*)d_in[6];
    const float* W2    = (const float*)d_in[7];
    const float* b2    = (const float*)d_in[8];
    const float* gamma = (const float*)d_in[9];
    const float* beta  = (const float*)d_in[10];

    const int N = in_sizes[0] / D_DIM;              // 50000
    const int E = in_sizes[2] / EDGE_DIM;           // 600000
    const int L = in_sizes[3] / (EDGE_DIM * D_DIM); // 3

    const int* src = ei;
    const int* dst = ei + E;

    float* out = (float*)d_out;

    char* wp = (char*)d_ws;
    auto take = [&wp](size_t bytes) {
        char* r = wp;
        wp += (bytes + 15) & ~(size_t)15;
        return r;
    };
    float*     agg     = (float*)    take((size_t)N * D_DIM * 4);
    ushort_t*  h16     = (ushort_t*) take((size_t)N * D_DIM * 2);
    unsigned*  x16d    = (unsigned*) take((size_t)N * D_DIM * 2);
    float*     sums    = (float*)    take(256 * 4);
    float*     scsh    = (float*)    take(256 * 4);
    unsigned*  wl16d   = (unsigned*) take(16 * 128 * 4);
    int*       cnt     = (int*)      take((size_t)N * 4);
    int*       row_off = (int*)      take((size_t)(N + 1) * 4);
    int*       cur     = (int*)      take((size_t)N * 4);
    int*       blksum  = (int*)      take(256 * 4);
    int*       srcs    = (int*)      take((size_t)E * 4);
    uint4*     ea16q   = (uint4*)    take((size_t)E * 64);

    const int gemmBlocks = (N + 127) / 128;
    const int scanBlocks = (N + 2047) / 2048;

    hipMemsetAsync(cnt, 0, (size_t)N * sizeof(int), stream);
    hist_kernel<<<1024, 256, 0, stream>>>(dst, cnt, E);
    scan_local_kernel<<<scanBlocks, 256, 0, stream>>>(cnt, row_off, blksum, N);
    scan_tops_kernel<<<1, 64, 0, stream>>>(blksum, row_off, N, scanBlocks);
    scan_add_kernel<<<scanBlocks, 256, 0, stream>>>(row_off, cur, blksum, N);
    scatter_conv_kernel<<<1024, 256, 0, stream>>>(src, dst, ea, cur, srcs, ea16q, E);

    for (int l = 0; l < L; ++l) {
        hipMemsetAsync(sums, 0, 256 * sizeof(float), stream);

        const float* Wl_l = W_lin + (size_t)l * EDGE_DIM * D_DIM;
        const float* bl_l = b_lin + (size_t)l * D_DIM;
        const float* W1_l = W1 + (size_t)l * D_DIM * D_DIM;
        const float* b1_l = b1 + (size_t)l * D_DIM;
        const float* W2_l = W2 + (size_t)l * D_DIM * D_DIM;
        const float* b2_l = b2 + (size_t)l * D_DIM;

        if (l == 0)
            xprep0_kernel<<<1024, 256, 0, stream>>>(x_in, (uint2*)x16d, N);
        else
            apply_kernel<0><<<1024, 256, 0, stream>>>(h16, scsh, (uint2*)x16d, nullptr, N);

        wl_build_kernel<<<1, 256, 0, stream>>>(Wl_l, wl16d);

        edge_agg_kernel<<<2048, 256, 0, stream>>>(
            x16d, srcs, ea16q, row_off, wl16d, bl_l, agg, N);

        fused_mlp_kernel<<<gemmBlocks, 256, 0, stream>>>(
            x16d, agg, W1_l, b1_l, W2_l, b2_l, h16, sums, N);

        bn_finalize_kernel<<<1, 128, 0, stream>>>(
            sums, gamma + (size_t)l * D_DIM, beta + (size_t)l * D_DIM,
            scsh, 1.f / (float)N);
    }

    apply_kernel<1><<<1024, 256, 0, stream>>>(h16, scsh, nullptr, out, N);
}